// Round 6
// baseline (370.895 us; speedup 1.0000x reference)
//
#include <hip/hip_runtime.h>
#include <math.h>

#define EPS 1e-16f
__device__ __forceinline__ float lrelu(float v) { return v > 0.0f ? v : 0.2f * v; }

typedef float f32x32 __attribute__((ext_vector_type(32)));   // 32 VGPRs, SSA value -> cannot be stack-demoted

// ---------------- CSR build ----------------
__global__ void k_zero(int* __restrict__ deg, int N) {
    int i = blockIdx.x * 256 + threadIdx.x;
    if (i < N) deg[i] = 0;
}

__global__ void k_deg(const int* __restrict__ dst, int* __restrict__ deg, int E) {
    int e = blockIdx.x * 256 + threadIdx.x;
    if (e < E) atomicAdd(&deg[dst[e]], 1);
}

// multi-block scan: per-block local inclusive scan + block sums
__global__ __launch_bounds__(1024) void k_scan_local(const int* __restrict__ deg,
                                                     int* __restrict__ rowptr,
                                                     int* __restrict__ blocksum, int N) {
    __shared__ int sdata[1024];
    int i = blockIdx.x * 1024 + threadIdx.x;
    int v = (i < N) ? deg[i] : 0;
    sdata[threadIdx.x] = v;
    __syncthreads();
    for (int off = 1; off < 1024; off <<= 1) {
        int t = (threadIdx.x >= (unsigned)off) ? sdata[threadIdx.x - off] : 0;
        __syncthreads();
        sdata[threadIdx.x] += t;
        __syncthreads();
    }
    if (i < N) rowptr[i + 1] = sdata[threadIdx.x];
    if (threadIdx.x == 1023) blocksum[blockIdx.x] = sdata[1023];
}

// exclusive scan of <=64 block sums in one wave
__global__ void k_scan_sums(const int* __restrict__ blocksum, int* __restrict__ blockoff, int nb) {
    int lane = threadIdx.x;
    int v = (lane < nb) ? blocksum[lane] : 0;
    int incl = v;
#pragma unroll
    for (int off = 1; off < 64; off <<= 1) {
        int t = __shfl_up(incl, off);
        if (lane >= off) incl += t;
    }
    if (lane < nb) blockoff[lane] = incl - v;
}

__global__ void k_scan_add(int* __restrict__ rowptr, const int* __restrict__ blockoff,
                           const int* __restrict__ deg, int* __restrict__ cursor, int N) {
    int i = blockIdx.x * 256 + threadIdx.x;
    if (i >= N) return;
    int val = rowptr[i + 1] + blockoff[i >> 10];
    rowptr[i + 1] = val;
    cursor[i] = val - deg[i];
    if (i == 0) rowptr[0] = 0;
}

__global__ void k_scatter(const int* __restrict__ src, const int* __restrict__ dst,
                          int* __restrict__ cursor, int* __restrict__ ssrc, int E) {
    int e = blockIdx.x * 256 + threadIdx.x;
    if (e >= E) return;
    int pos = atomicAdd(&cursor[dst[e]], 1);
    ssrc[pos] = src[e];
}

// unrolled 8-k4 chunk of the inner product: 32 k-steps against one 32-wide W vector
#define DO_CHUNK(wv, base)                                   \
    {                                                        \
        _Pragma("unroll")                                    \
        for (int k4 = 0; k4 < 8; k4++) {                     \
            float4 xv = xr[(base) + k4];                     \
            acc = fmaf(xv.x, wv[4 * k4 + 0], acc);           \
            acc = fmaf(xv.y, wv[4 * k4 + 1], acc);           \
            acc = fmaf(xv.z, wv[4 * k4 + 2], acc);           \
            acc = fmaf(xv.w, wv[4 * k4 + 3], acc);           \
        }                                                    \
    }

// ---------------- layer 1 GEMM: x[N,128] @ W1[128,64] -> h1, + attention dots ----------------
// lane = output col; W column in 4x f32x32 vector registers (ext_vector_type defeats the
// SROA failure that spilled float w[128] to scratch in R4/R5); x row is wave-uniform
// (readfirstlane'd wave id -> scalar loads).
#define R1 16   // rows per wave
__global__ __launch_bounds__(256, 1) void k_gemm1(
    const float* __restrict__ x, const float* __restrict__ W1,
    const float* __restrict__ att_src1, const float* __restrict__ att_dst1,
    float* __restrict__ h1, float* __restrict__ a_src1, float* __restrict__ a_dst1, int N) {
    int lane = threadIdx.x & 63;
    int wave = __builtin_amdgcn_readfirstlane((int)((blockIdx.x * 256 + threadIdx.x) >> 6));
    int r0 = wave * R1;
    if (r0 >= N) return;
    int r1 = min(r0 + R1, N);
    const float* Wp = W1 + lane;
    f32x32 w0, w1, w2, w3;
#pragma unroll
    for (int k = 0; k < 32; k++) {
        w0[k] = Wp[(k)      * 64];
        w1[k] = Wp[(k + 32) * 64];
        w2[k] = Wp[(k + 64) * 64];
        w3[k] = Wp[(k + 96) * 64];
    }
    float as = att_src1[lane], ad = att_dst1[lane];
    for (int r = r0; r < r1; r++) {
        const float4* xr = (const float4*)(x + (size_t)r * 128);
        float acc = 0.0f;
        DO_CHUNK(w0, 0)
        DO_CHUNK(w1, 8)
        DO_CHUNK(w2, 16)
        DO_CHUNK(w3, 24)
        h1[(size_t)r * 64 + lane] = acc;
        float ps = acc * as, pd = acc * ad;
#pragma unroll
        for (int off = 4; off; off >>= 1) {
            ps += __shfl_down(ps, off, 8);
            pd += __shfl_down(pd, off, 8);
        }
        if ((lane & 7) == 0) {
            a_src1[r * 8 + (lane >> 3)] = ps;
            a_dst1[r * 8 + (lane >> 3)] = pd;
        }
    }
}

// ---------------- layer 1: per-dst-node softmax + aggregate (one wave per node) ----------------
// no max subtraction (softmax shift-invariant; logits are O(1))
__global__ __launch_bounds__(256) void k_node_agg1(
    const int* __restrict__ rowptr, const int* __restrict__ ssrc,
    const float* __restrict__ a_src1, const float* __restrict__ a_dst1,
    const float* __restrict__ h1, const float* __restrict__ bias1,
    float* __restrict__ xx, int N) {
    int d = (blockIdx.x * 256 + threadIdx.x) >> 6;
    int lane = threadIdx.x & 63;
    if (d >= N) return;
    int start = rowptr[d], end = rowptr[d + 1];
    int hcol = lane >> 3;   // head owning this output col
    int h8 = lane & 7;      // head this lane covers in edge-parallel phase
    int eoff = lane >> 3;   // edge-in-chunk this lane covers in edge-parallel phase
    float adst8 = a_dst1[d * 8 + h8];
    float acc0 = 0.0f, acc1 = 0.0f, lsumA = 0.0f;
    int base = start;
    for (; base + 8 <= end; base += 8) {
        // phase A: 8 edges x 8 heads in parallel
        int s_l = ssrc[base + eoff];
        float ex_l = __expf(lrelu(a_src1[(size_t)s_l * 8 + h8] + adst8));
        lsumA += ex_l;
        // phase B: broadcast (s,ex) via shuffle, 8 independent gathers
        int s0 = __shfl(s_l, 0),  s1 = __shfl(s_l, 8),  s2 = __shfl(s_l, 16), s3 = __shfl(s_l, 24);
        int s4 = __shfl(s_l, 32), s5 = __shfl(s_l, 40), s6 = __shfl(s_l, 48), s7 = __shfl(s_l, 56);
        float f0 = __shfl(ex_l, hcol),      f1 = __shfl(ex_l, 8 + hcol);
        float f2 = __shfl(ex_l, 16 + hcol), f3 = __shfl(ex_l, 24 + hcol);
        float f4 = __shfl(ex_l, 32 + hcol), f5 = __shfl(ex_l, 40 + hcol);
        float f6 = __shfl(ex_l, 48 + hcol), f7 = __shfl(ex_l, 56 + hcol);
        float g0 = h1[(size_t)s0 * 64 + lane], g1 = h1[(size_t)s1 * 64 + lane];
        float g2 = h1[(size_t)s2 * 64 + lane], g3 = h1[(size_t)s3 * 64 + lane];
        float g4 = h1[(size_t)s4 * 64 + lane], g5 = h1[(size_t)s5 * 64 + lane];
        float g6 = h1[(size_t)s6 * 64 + lane], g7 = h1[(size_t)s7 * 64 + lane];
        acc0 = fmaf(f0, g0, acc0); acc1 = fmaf(f1, g1, acc1);
        acc0 = fmaf(f2, g2, acc0); acc1 = fmaf(f3, g3, acc1);
        acc0 = fmaf(f4, g4, acc0); acc1 = fmaf(f5, g5, acc1);
        acc0 = fmaf(f6, g6, acc0); acc1 = fmaf(f7, g7, acc1);
    }
    int ecnt = end - base;
    if (ecnt > 0) {
        int s_l = 0; float ex_l = 0.0f;
        if (eoff < ecnt) {
            s_l = ssrc[base + eoff];
            ex_l = __expf(lrelu(a_src1[(size_t)s_l * 8 + h8] + adst8));
        }
        lsumA += ex_l;
        for (int j = 0; j < ecnt; j++) {
            int sj = __shfl(s_l, j * 8);
            float fj = __shfl(ex_l, j * 8 + hcol);
            acc0 = fmaf(fj, h1[(size_t)sj * 64 + lane], acc0);
        }
    }
    // denom: reduce lsumA over edge-offset bits (3..5); then broadcast head hcol's sum
    float t = lsumA;
    t += __shfl_xor(t, 8); t += __shfl_xor(t, 16); t += __shfl_xor(t, 32);
    float lsum = __shfl(t, hcol);
    float o = (acc0 + acc1) / (lsum + EPS) + bias1[lane];
    xx[(size_t)d * 64 + lane] = o > 0.0f ? o : expm1f(o);   // ELU
}

// ---------------- layer 2 GEMM fused with attention dots ----------------
// xx[N,64] @ W2[64,40] -> h2 ; a_src2/a_dst2 = h2 . att2  (all-lane xor reduce)
#define R2 16
__global__ __launch_bounds__(256, 1) void k_gemm2(
    const float* __restrict__ xx, const float* __restrict__ W2,
    const float* __restrict__ att_src2, const float* __restrict__ att_dst2,
    float* __restrict__ h2, float* __restrict__ a_src2, float* __restrict__ a_dst2, int N) {
    int lane = threadIdx.x & 63;
    int wave = __builtin_amdgcn_readfirstlane((int)((blockIdx.x * 256 + threadIdx.x) >> 6));
    int r0 = wave * R2;
    if (r0 >= N) return;
    int r1 = min(r0 + R2, N);
    bool act = lane < 40;
    f32x32 w0, w1;
#pragma unroll
    for (int k = 0; k < 32; k++) {
        w0[k] = act ? W2[(k)      * 40 + lane] : 0.0f;
        w1[k] = act ? W2[(k + 32) * 40 + lane] : 0.0f;
    }
    float as = act ? att_src2[lane] : 0.0f;
    float ad = act ? att_dst2[lane] : 0.0f;
    for (int r = r0; r < r1; r++) {
        const float4* xr = (const float4*)(xx + (size_t)r * 64);
        float acc = 0.0f;
        DO_CHUNK(w0, 0)
        DO_CHUNK(w1, 8)
        if (act) h2[(size_t)r * 40 + lane] = acc;
        float ps = acc * as, pd = acc * ad;
#pragma unroll
        for (int off = 32; off; off >>= 1) {
            ps += __shfl_xor(ps, off);
            pd += __shfl_xor(pd, off);
        }
        if (lane == 0) { a_src2[r] = ps; a_dst2[r] = pd; }
    }
}

// ---------------- layer 2: per-dst-node softmax + aggregate ----------------
__global__ __launch_bounds__(256) void k_node_agg2(
    const int* __restrict__ rowptr, const int* __restrict__ ssrc,
    const float* __restrict__ a_src2, const float* __restrict__ a_dst2,
    const float* __restrict__ h2, const float* __restrict__ bias2,
    float* __restrict__ out, int N) {
    int d = (blockIdx.x * 256 + threadIdx.x) >> 6;
    int lane = threadIdx.x & 63;
    if (d >= N) return;
    int start = rowptr[d], end = rowptr[d + 1];
    float adst = a_dst2[d];
    bool act = lane < 40;
    float acc0 = 0.0f, acc1 = 0.0f, lsumA = 0.0f;
    for (int base = start; base < end; base += 64) {
        int ecnt = min(64, end - base);
        int s_l = 0; float ex_l = 0.0f;
        if (lane < ecnt) {
            s_l = ssrc[base + lane];
            ex_l = __expf(lrelu(a_src2[s_l] + adst));
        }
        lsumA += ex_l;
        int j = 0;
        for (; j + 8 <= ecnt; j += 8) {
            int s0 = __shfl(s_l, j),     s1 = __shfl(s_l, j + 1), s2 = __shfl(s_l, j + 2), s3 = __shfl(s_l, j + 3);
            int s4 = __shfl(s_l, j + 4), s5 = __shfl(s_l, j + 5), s6 = __shfl(s_l, j + 6), s7 = __shfl(s_l, j + 7);
            float f0 = __shfl(ex_l, j),     f1 = __shfl(ex_l, j + 1), f2 = __shfl(ex_l, j + 2), f3 = __shfl(ex_l, j + 3);
            float f4 = __shfl(ex_l, j + 4), f5 = __shfl(ex_l, j + 5), f6 = __shfl(ex_l, j + 6), f7 = __shfl(ex_l, j + 7);
            float g0 = act ? h2[(size_t)s0 * 40 + lane] : 0.0f;
            float g1 = act ? h2[(size_t)s1 * 40 + lane] : 0.0f;
            float g2 = act ? h2[(size_t)s2 * 40 + lane] : 0.0f;
            float g3 = act ? h2[(size_t)s3 * 40 + lane] : 0.0f;
            float g4 = act ? h2[(size_t)s4 * 40 + lane] : 0.0f;
            float g5 = act ? h2[(size_t)s5 * 40 + lane] : 0.0f;
            float g6 = act ? h2[(size_t)s6 * 40 + lane] : 0.0f;
            float g7 = act ? h2[(size_t)s7 * 40 + lane] : 0.0f;
            acc0 = fmaf(f0, g0, acc0); acc1 = fmaf(f1, g1, acc1);
            acc0 = fmaf(f2, g2, acc0); acc1 = fmaf(f3, g3, acc1);
            acc0 = fmaf(f4, g4, acc0); acc1 = fmaf(f5, g5, acc1);
            acc0 = fmaf(f6, g6, acc0); acc1 = fmaf(f7, g7, acc1);
        }
        for (; j < ecnt; j++) {
            int sj = __shfl(s_l, j);
            float fj = __shfl(ex_l, j);
            float g = act ? h2[(size_t)sj * 40 + lane] : 0.0f;
            acc0 = fmaf(fj, g, acc0);
        }
    }
    float t = lsumA;
#pragma unroll
    for (int off = 32; off; off >>= 1) t += __shfl_xor(t, off);
    if (act) out[(size_t)d * 40 + lane] = (acc0 + acc1) / (t + EPS) + bias2[lane];
}

// ---------------- launch ----------------
extern "C" void kernel_launch(void* const* d_in, const int* in_sizes, int n_in,
                              void* d_out, int out_size, void* d_ws, size_t ws_size,
                              hipStream_t stream) {
    const float* x        = (const float*)d_in[0];
    const int*   ei       = (const int*)d_in[1];
    const float* W1       = (const float*)d_in[2];
    const float* att_src1 = (const float*)d_in[3];
    const float* att_dst1 = (const float*)d_in[4];
    const float* bias1    = (const float*)d_in[5];
    const float* W2       = (const float*)d_in[6];
    const float* att_src2 = (const float*)d_in[7];
    const float* att_dst2 = (const float*)d_in[8];
    const float* bias2    = (const float*)d_in[9];
    float* out = (float*)d_out;

    const int N = in_sizes[0] / 128;   // 50000
    const int E = in_sizes[1] / 2;     // 800000
    const int* src = ei;
    const int* dst = ei + E;

    // workspace layout
    float* ws = (float*)d_ws;
    size_t off = 0;
    int*   deg      = (int*)(ws + off); off += (size_t)N;
    int*   rowptr   = (int*)(ws + off); off += (size_t)N + 1;
    int*   cursor   = (int*)(ws + off); off += (size_t)N;
    int*   blocksum = (int*)(ws + off); off += 64;
    int*   blockoff = (int*)(ws + off); off += 64;
    int*   ssrc     = (int*)(ws + off); off += (size_t)E;
    float* h1       = ws + off; off += (size_t)N * 64;
    float* a_src1   = ws + off; off += (size_t)N * 8;
    float* a_dst1   = ws + off; off += (size_t)N * 8;
    float* xx       = ws + off; off += (size_t)N * 64;
    float* h2       = ws + off; off += (size_t)N * 40;
    float* a_src2   = ws + off; off += (size_t)N;
    float* a_dst2   = ws + off; off += (size_t)N;

    const int B = 256;
    auto g = [](int n) { return (n + 255) / 256; };
    int nb = (N + 1023) / 1024;   // 49

    // CSR build (dst-grouped)
    k_zero<<<g(N), B, 0, stream>>>(deg, N);
    k_deg<<<g(E), B, 0, stream>>>(dst, deg, E);
    k_scan_local<<<nb, 1024, 0, stream>>>(deg, rowptr, blocksum, N);
    k_scan_sums<<<1, 64, 0, stream>>>(blocksum, blockoff, nb);
    k_scan_add<<<g(N), B, 0, stream>>>(rowptr, blockoff, deg, cursor, N);
    k_scatter<<<g(E), B, 0, stream>>>(src, dst, cursor, ssrc, E);

    // layer 1
    int waves1 = (N + R1 - 1) / R1;
    k_gemm1<<<(waves1 + 3) / 4, B, 0, stream>>>(x, W1, att_src1, att_dst1, h1, a_src1, a_dst1, N);
    k_node_agg1<<<(N + 3) / 4, B, 0, stream>>>(rowptr, ssrc, a_src1, a_dst1, h1, bias1, xx, N);

    // layer 2 (gemm + attn dots fused)
    int waves2 = (N + R2 - 1) / R2;
    k_gemm2<<<(waves2 + 3) / 4, B, 0, stream>>>(xx, W2, att_src2, att_dst2, h2, a_src2, a_dst2, N);
    k_node_agg2<<<(N + 3) / 4, B, 0, stream>>>(rowptr, ssrc, a_src2, a_dst2, h2, bias2, out, N);
}

// Round 7
// 301.711 us; speedup vs baseline: 1.2293x; 1.2293x over previous
//
#include <hip/hip_runtime.h>
#include <math.h>

#define EPS 1e-16f
__device__ __forceinline__ float lrelu(float v) { return v > 0.0f ? v : 0.2f * v; }

// ---------------- CSR build ----------------
__global__ void k_zero(int* __restrict__ deg, int N) {
    int i = blockIdx.x * 256 + threadIdx.x;
    if (i < N) deg[i] = 0;
}

__global__ void k_deg(const int* __restrict__ dst, int* __restrict__ deg, int E) {
    int e = blockIdx.x * 256 + threadIdx.x;
    if (e < E) atomicAdd(&deg[dst[e]], 1);
}

// multi-block scan: per-block local inclusive scan + block sums
__global__ __launch_bounds__(1024) void k_scan_local(const int* __restrict__ deg,
                                                     int* __restrict__ rowptr,
                                                     int* __restrict__ blocksum, int N) {
    __shared__ int sdata[1024];
    int i = blockIdx.x * 1024 + threadIdx.x;
    int v = (i < N) ? deg[i] : 0;
    sdata[threadIdx.x] = v;
    __syncthreads();
    for (int off = 1; off < 1024; off <<= 1) {
        int t = (threadIdx.x >= (unsigned)off) ? sdata[threadIdx.x - off] : 0;
        __syncthreads();
        sdata[threadIdx.x] += t;
        __syncthreads();
    }
    if (i < N) rowptr[i + 1] = sdata[threadIdx.x];
    if (threadIdx.x == 1023) blocksum[blockIdx.x] = sdata[1023];
}

// exclusive scan of <=64 block sums in one wave
__global__ void k_scan_sums(const int* __restrict__ blocksum, int* __restrict__ blockoff, int nb) {
    int lane = threadIdx.x;
    int v = (lane < nb) ? blocksum[lane] : 0;
    int incl = v;
#pragma unroll
    for (int off = 1; off < 64; off <<= 1) {
        int t = __shfl_up(incl, off);
        if (lane >= off) incl += t;
    }
    if (lane < nb) blockoff[lane] = incl - v;
}

__global__ void k_scan_add(int* __restrict__ rowptr, const int* __restrict__ blockoff,
                           const int* __restrict__ deg, int* __restrict__ cursor, int N) {
    int i = blockIdx.x * 256 + threadIdx.x;
    if (i >= N) return;
    int val = rowptr[i + 1] + blockoff[i >> 10];
    rowptr[i + 1] = val;
    cursor[i] = val - deg[i];
    if (i == 0) rowptr[0] = 0;
}

__global__ void k_scatter(const int* __restrict__ src, const int* __restrict__ dst,
                          int* __restrict__ cursor, int* __restrict__ ssrc, int E) {
    int e = blockIdx.x * 256 + threadIdx.x;
    if (e >= E) return;
    int pos = atomicAdd(&cursor[dst[e]], 1);
    ssrc[pos] = src[e];
}

// ---------------- layer 1 GEMM: x[N,128] @ W1[128,64] -> h1, + fused attention dots ----
// Register-tiled LDS GEMM: BM=64, BN=64, K=128 whole. 256 threads = 16x16 grid,
// 4x4 micro-tile each. Pitches 129/65 (== 1 mod 32) -> <=2-way LDS conflicts (free).
#define LDK1 129
#define LDN1 65
__global__ __launch_bounds__(256, 2) void k_gemm1(
    const float* __restrict__ x, const float* __restrict__ W1,
    const float* __restrict__ att_src1, const float* __restrict__ att_dst1,
    float* __restrict__ h1, float* __restrict__ a_src1, float* __restrict__ a_dst1, int N) {
    __shared__ float sX[64 * LDK1];    // [m][k]
    __shared__ float sW[128 * LDN1];   // [k][n]
    int t = threadIdx.x;
    int r0 = blockIdx.x * 64;
    // stage W1 (128x64): float4 global reads, scalar LDS writes
    for (int i = t; i < 2048; i += 256) {        // i = k*16 + n4
        int k = i >> 4, n4 = i & 15;
        float4 v = ((const float4*)W1)[i];
        float* p = sW + k * LDN1 + 4 * n4;
        p[0] = v.x; p[1] = v.y; p[2] = v.z; p[3] = v.w;
    }
    // stage x rows r0..r0+63 (zero-pad tail)
    for (int i = t; i < 2048; i += 256) {        // i = m*32 + k4
        int m = i >> 5, k4 = i & 31;
        int r = r0 + m;
        float4 v = make_float4(0.f, 0.f, 0.f, 0.f);
        if (r < N) v = ((const float4*)(x + (size_t)r * 128))[k4];
        float* p = sX + m * LDK1 + 4 * k4;
        p[0] = v.x; p[1] = v.y; p[2] = v.z; p[3] = v.w;
    }
    __syncthreads();
    int tx = t & 15, ty = t >> 4;                // rows 4*tx.., cols 4*ty..
    const float* pA = sX + 4 * tx * LDK1;
    const float* pB = sW + 4 * ty;
    float c[4][4] = {{0.f}};
#pragma unroll 8
    for (int k = 0; k < 128; k++) {
        float a0 = pA[k], a1 = pA[LDK1 + k], a2 = pA[2 * LDK1 + k], a3 = pA[3 * LDK1 + k];
        const float* pb = pB + k * LDN1;
        float b0 = pb[0], b1 = pb[1], b2 = pb[2], b3 = pb[3];
        c[0][0] = fmaf(a0, b0, c[0][0]); c[0][1] = fmaf(a0, b1, c[0][1]);
        c[0][2] = fmaf(a0, b2, c[0][2]); c[0][3] = fmaf(a0, b3, c[0][3]);
        c[1][0] = fmaf(a1, b0, c[1][0]); c[1][1] = fmaf(a1, b1, c[1][1]);
        c[1][2] = fmaf(a1, b2, c[1][2]); c[1][3] = fmaf(a1, b3, c[1][3]);
        c[2][0] = fmaf(a2, b0, c[2][0]); c[2][1] = fmaf(a2, b1, c[2][1]);
        c[2][2] = fmaf(a2, b2, c[2][2]); c[2][3] = fmaf(a2, b3, c[2][3]);
        c[3][0] = fmaf(a3, b0, c[3][0]); c[3][1] = fmaf(a3, b1, c[3][1]);
        c[3][2] = fmaf(a3, b2, c[3][2]); c[3][3] = fmaf(a3, b3, c[3][3]);
    }
    // epilogue: write h1, fused per-head attention dots.
    // cols 4ty..4ty+3 all lie in head ty>>1 (never cross an 8-boundary).
    float as0 = att_src1[4 * ty + 0], as1 = att_src1[4 * ty + 1],
          as2 = att_src1[4 * ty + 2], as3 = att_src1[4 * ty + 3];
    float ad0 = att_dst1[4 * ty + 0], ad1 = att_dst1[4 * ty + 1],
          ad2 = att_dst1[4 * ty + 2], ad3 = att_dst1[4 * ty + 3];
    __syncthreads();                              // done reading sX/sW; reuse sX as partials
    float* sPs = sX;                              // [row][17]
    float* sPd = sX + 64 * 17;
#pragma unroll
    for (int i = 0; i < 4; i++) {
        int row = 4 * tx + i;
        int r = r0 + row;
        if (r < N) {
            float4 hv = make_float4(c[i][0], c[i][1], c[i][2], c[i][3]);
            *((float4*)(h1 + (size_t)r * 64 + 4 * ty)) = hv;
        }
        sPs[row * 17 + ty] = fmaf(c[i][0], as0, fmaf(c[i][1], as1, fmaf(c[i][2], as2, c[i][3] * as3)));
        sPd[row * 17 + ty] = fmaf(c[i][0], ad0, fmaf(c[i][1], ad1, fmaf(c[i][2], ad2, c[i][3] * ad3)));
    }
    __syncthreads();
    for (int i = t; i < 512; i += 256) {          // i = row*8 + h
        int row = i >> 3, h = i & 7;
        int r = r0 + row;
        if (r < N) {
            a_src1[r * 8 + h] = sPs[row * 17 + 2 * h] + sPs[row * 17 + 2 * h + 1];
            a_dst1[r * 8 + h] = sPd[row * 17 + 2 * h] + sPd[row * 17 + 2 * h + 1];
        }
    }
}

// ---------------- layer 1: per-dst-node softmax + aggregate (one wave per node) ----------------
// no max subtraction (softmax shift-invariant; logits are O(1))
__global__ __launch_bounds__(256) void k_node_agg1(
    const int* __restrict__ rowptr, const int* __restrict__ ssrc,
    const float* __restrict__ a_src1, const float* __restrict__ a_dst1,
    const float* __restrict__ h1, const float* __restrict__ bias1,
    float* __restrict__ xx, int N) {
    int d = (blockIdx.x * 256 + threadIdx.x) >> 6;
    int lane = threadIdx.x & 63;
    if (d >= N) return;
    int start = rowptr[d], end = rowptr[d + 1];
    int hcol = lane >> 3;   // head owning this output col
    int h8 = lane & 7;      // head this lane covers in edge-parallel phase
    int eoff = lane >> 3;   // edge-in-chunk this lane covers in edge-parallel phase
    float adst8 = a_dst1[d * 8 + h8];
    float acc0 = 0.0f, acc1 = 0.0f, lsumA = 0.0f;
    int base = start;
    for (; base + 8 <= end; base += 8) {
        // phase A: 8 edges x 8 heads in parallel
        int s_l = ssrc[base + eoff];
        float ex_l = __expf(lrelu(a_src1[(size_t)s_l * 8 + h8] + adst8));
        lsumA += ex_l;
        // phase B: broadcast (s,ex) via shuffle, 8 independent gathers
        int s0 = __shfl(s_l, 0),  s1 = __shfl(s_l, 8),  s2 = __shfl(s_l, 16), s3 = __shfl(s_l, 24);
        int s4 = __shfl(s_l, 32), s5 = __shfl(s_l, 40), s6 = __shfl(s_l, 48), s7 = __shfl(s_l, 56);
        float f0 = __shfl(ex_l, hcol),      f1 = __shfl(ex_l, 8 + hcol);
        float f2 = __shfl(ex_l, 16 + hcol), f3 = __shfl(ex_l, 24 + hcol);
        float f4 = __shfl(ex_l, 32 + hcol), f5 = __shfl(ex_l, 40 + hcol);
        float f6 = __shfl(ex_l, 48 + hcol), f7 = __shfl(ex_l, 56 + hcol);
        float g0 = h1[(size_t)s0 * 64 + lane], g1 = h1[(size_t)s1 * 64 + lane];
        float g2 = h1[(size_t)s2 * 64 + lane], g3 = h1[(size_t)s3 * 64 + lane];
        float g4 = h1[(size_t)s4 * 64 + lane], g5 = h1[(size_t)s5 * 64 + lane];
        float g6 = h1[(size_t)s6 * 64 + lane], g7 = h1[(size_t)s7 * 64 + lane];
        acc0 = fmaf(f0, g0, acc0); acc1 = fmaf(f1, g1, acc1);
        acc0 = fmaf(f2, g2, acc0); acc1 = fmaf(f3, g3, acc1);
        acc0 = fmaf(f4, g4, acc0); acc1 = fmaf(f5, g5, acc1);
        acc0 = fmaf(f6, g6, acc0); acc1 = fmaf(f7, g7, acc1);
    }
    int ecnt = end - base;
    if (ecnt > 0) {
        int s_l = 0; float ex_l = 0.0f;
        if (eoff < ecnt) {
            s_l = ssrc[base + eoff];
            ex_l = __expf(lrelu(a_src1[(size_t)s_l * 8 + h8] + adst8));
        }
        lsumA += ex_l;
        for (int j = 0; j < ecnt; j++) {
            int sj = __shfl(s_l, j * 8);
            float fj = __shfl(ex_l, j * 8 + hcol);
            acc0 = fmaf(fj, h1[(size_t)sj * 64 + lane], acc0);
        }
    }
    // denom: reduce lsumA over edge-offset bits (3..5); then broadcast head hcol's sum
    float t = lsumA;
    t += __shfl_xor(t, 8); t += __shfl_xor(t, 16); t += __shfl_xor(t, 32);
    float lsum = __shfl(t, hcol);
    float o = (acc0 + acc1) / (lsum + EPS) + bias1[lane];
    xx[(size_t)d * 64 + lane] = o > 0.0f ? o : expm1f(o);   // ELU
}

// ---------------- layer 2 GEMM: xx[N,64] @ W2[64,40] -> h2, + fused attention dots ----
// Same skeleton: BM=64, BN=40 (ty<10 active), K=64 whole.
#define LDK2 65
#define LDN2 41
__global__ __launch_bounds__(256, 2) void k_gemm2(
    const float* __restrict__ xx, const float* __restrict__ W2,
    const float* __restrict__ att_src2, const float* __restrict__ att_dst2,
    float* __restrict__ h2, float* __restrict__ a_src2, float* __restrict__ a_dst2, int N) {
    __shared__ float sX[64 * LDK2];    // [m][k]
    __shared__ float sW[64 * LDN2];    // [k][n]
    int t = threadIdx.x;
    int r0 = blockIdx.x * 64;
    // stage W2 (64x40): 640 float4s
    for (int i = t; i < 640; i += 256) {          // i = k*10 + n4
        int k = i / 10, n4 = i - k * 10;
        float4 v = ((const float4*)W2)[i];
        float* p = sW + k * LDN2 + 4 * n4;
        p[0] = v.x; p[1] = v.y; p[2] = v.z; p[3] = v.w;
    }
    // stage xx rows (64 x 16 float4s)
    for (int i = t; i < 1024; i += 256) {         // i = m*16 + k4
        int m = i >> 4, k4 = i & 15;
        int r = r0 + m;
        float4 v = make_float4(0.f, 0.f, 0.f, 0.f);
        if (r < N) v = ((const float4*)(xx + (size_t)r * 64))[k4];
        float* p = sX + m * LDK2 + 4 * k4;
        p[0] = v.x; p[1] = v.y; p[2] = v.z; p[3] = v.w;
    }
    __syncthreads();
    int tx = t & 15, ty = t >> 4;
    bool act = ty < 10;
    float c[4][4] = {{0.f}};
    if (act) {
        const float* pA = sX + 4 * tx * LDK2;
        const float* pB = sW + 4 * ty;
#pragma unroll 8
        for (int k = 0; k < 64; k++) {
            float a0 = pA[k], a1 = pA[LDK2 + k], a2 = pA[2 * LDK2 + k], a3 = pA[3 * LDK2 + k];
            const float* pb = pB + k * LDN2;
            float b0 = pb[0], b1 = pb[1], b2 = pb[2], b3 = pb[3];
            c[0][0] = fmaf(a0, b0, c[0][0]); c[0][1] = fmaf(a0, b1, c[0][1]);
            c[0][2] = fmaf(a0, b2, c[0][2]); c[0][3] = fmaf(a0, b3, c[0][3]);
            c[1][0] = fmaf(a1, b0, c[1][0]); c[1][1] = fmaf(a1, b1, c[1][1]);
            c[1][2] = fmaf(a1, b2, c[1][2]); c[1][3] = fmaf(a1, b3, c[1][3]);
            c[2][0] = fmaf(a2, b0, c[2][0]); c[2][1] = fmaf(a2, b1, c[2][1]);
            c[2][2] = fmaf(a2, b2, c[2][2]); c[2][3] = fmaf(a2, b3, c[2][3]);
            c[3][0] = fmaf(a3, b0, c[3][0]); c[3][1] = fmaf(a3, b1, c[3][1]);
            c[3][2] = fmaf(a3, b2, c[3][2]); c[3][3] = fmaf(a3, b3, c[3][3]);
        }
    }
    float as0 = 0.f, as1 = 0.f, as2 = 0.f, as3 = 0.f;
    float ad0 = 0.f, ad1 = 0.f, ad2 = 0.f, ad3 = 0.f;
    if (act) {
        as0 = att_src2[4 * ty + 0]; as1 = att_src2[4 * ty + 1];
        as2 = att_src2[4 * ty + 2]; as3 = att_src2[4 * ty + 3];
        ad0 = att_dst2[4 * ty + 0]; ad1 = att_dst2[4 * ty + 1];
        ad2 = att_dst2[4 * ty + 2]; ad3 = att_dst2[4 * ty + 3];
    }
    __syncthreads();                              // reuse sX as partials [row][11]
    float* sPs = sX;
    float* sPd = sX + 64 * 11;
#pragma unroll
    for (int i = 0; i < 4; i++) {
        int row = 4 * tx + i;
        int r = r0 + row;
        if (act) {
            if (r < N) {
                float4 hv = make_float4(c[i][0], c[i][1], c[i][2], c[i][3]);
                *((float4*)(h2 + (size_t)r * 40 + 4 * ty)) = hv;
            }
            sPs[row * 11 + ty] = fmaf(c[i][0], as0, fmaf(c[i][1], as1, fmaf(c[i][2], as2, c[i][3] * as3)));
            sPd[row * 11 + ty] = fmaf(c[i][0], ad0, fmaf(c[i][1], ad1, fmaf(c[i][2], ad2, c[i][3] * ad3)));
        }
    }
    __syncthreads();
    if (t < 64) {
        int r = r0 + t;
        if (r < N) {
            float ps = 0.f, pd = 0.f;
#pragma unroll
            for (int j = 0; j < 10; j++) {
                ps += sPs[t * 11 + j];
                pd += sPd[t * 11 + j];
            }
            a_src2[r] = ps;
            a_dst2[r] = pd;
        }
    }
}

// ---------------- layer 2: per-dst-node softmax + aggregate ----------------
__global__ __launch_bounds__(256) void k_node_agg2(
    const int* __restrict__ rowptr, const int* __restrict__ ssrc,
    const float* __restrict__ a_src2, const float* __restrict__ a_dst2,
    const float* __restrict__ h2, const float* __restrict__ bias2,
    float* __restrict__ out, int N) {
    int d = (blockIdx.x * 256 + threadIdx.x) >> 6;
    int lane = threadIdx.x & 63;
    if (d >= N) return;
    int start = rowptr[d], end = rowptr[d + 1];
    float adst = a_dst2[d];
    bool act = lane < 40;
    float acc0 = 0.0f, acc1 = 0.0f, lsumA = 0.0f;
    for (int base = start; base < end; base += 64) {
        int ecnt = min(64, end - base);
        int s_l = 0; float ex_l = 0.0f;
        if (lane < ecnt) {
            s_l = ssrc[base + lane];
            ex_l = __expf(lrelu(a_src2[s_l] + adst));
        }
        lsumA += ex_l;
        int j = 0;
        for (; j + 8 <= ecnt; j += 8) {
            int s0 = __shfl(s_l, j),     s1 = __shfl(s_l, j + 1), s2 = __shfl(s_l, j + 2), s3 = __shfl(s_l, j + 3);
            int s4 = __shfl(s_l, j + 4), s5 = __shfl(s_l, j + 5), s6 = __shfl(s_l, j + 6), s7 = __shfl(s_l, j + 7);
            float f0 = __shfl(ex_l, j),     f1 = __shfl(ex_l, j + 1), f2 = __shfl(ex_l, j + 2), f3 = __shfl(ex_l, j + 3);
            float f4 = __shfl(ex_l, j + 4), f5 = __shfl(ex_l, j + 5), f6 = __shfl(ex_l, j + 6), f7 = __shfl(ex_l, j + 7);
            float g0 = act ? h2[(size_t)s0 * 40 + lane] : 0.0f;
            float g1 = act ? h2[(size_t)s1 * 40 + lane] : 0.0f;
            float g2 = act ? h2[(size_t)s2 * 40 + lane] : 0.0f;
            float g3 = act ? h2[(size_t)s3 * 40 + lane] : 0.0f;
            float g4 = act ? h2[(size_t)s4 * 40 + lane] : 0.0f;
            float g5 = act ? h2[(size_t)s5 * 40 + lane] : 0.0f;
            float g6 = act ? h2[(size_t)s6 * 40 + lane] : 0.0f;
            float g7 = act ? h2[(size_t)s7 * 40 + lane] : 0.0f;
            acc0 = fmaf(f0, g0, acc0); acc1 = fmaf(f1, g1, acc1);
            acc0 = fmaf(f2, g2, acc0); acc1 = fmaf(f3, g3, acc1);
            acc0 = fmaf(f4, g4, acc0); acc1 = fmaf(f5, g5, acc1);
            acc0 = fmaf(f6, g6, acc0); acc1 = fmaf(f7, g7, acc1);
        }
        for (; j < ecnt; j++) {
            int sj = __shfl(s_l, j);
            float fj = __shfl(ex_l, j);
            float g = act ? h2[(size_t)sj * 40 + lane] : 0.0f;
            acc0 = fmaf(fj, g, acc0);
        }
    }
    float t = lsumA;
#pragma unroll
    for (int off = 32; off; off >>= 1) t += __shfl_xor(t, off);
    if (act) out[(size_t)d * 40 + lane] = (acc0 + acc1) / (t + EPS) + bias2[lane];
}

// ---------------- launch ----------------
extern "C" void kernel_launch(void* const* d_in, const int* in_sizes, int n_in,
                              void* d_out, int out_size, void* d_ws, size_t ws_size,
                              hipStream_t stream) {
    const float* x        = (const float*)d_in[0];
    const int*   ei       = (const int*)d_in[1];
    const float* W1       = (const float*)d_in[2];
    const float* att_src1 = (const float*)d_in[3];
    const float* att_dst1 = (const float*)d_in[4];
    const float* bias1    = (const float*)d_in[5];
    const float* W2       = (const float*)d_in[6];
    const float* att_src2 = (const float*)d_in[7];
    const float* att_dst2 = (const float*)d_in[8];
    const float* bias2    = (const float*)d_in[9];
    float* out = (float*)d_out;

    const int N = in_sizes[0] / 128;   // 50000
    const int E = in_sizes[1] / 2;     // 800000
    const int* src = ei;
    const int* dst = ei + E;

    // workspace layout
    float* ws = (float*)d_ws;
    size_t off = 0;
    int*   deg      = (int*)(ws + off); off += (size_t)N;
    int*   rowptr   = (int*)(ws + off); off += (size_t)N + 1;
    int*   cursor   = (int*)(ws + off); off += (size_t)N;
    int*   blocksum = (int*)(ws + off); off += 64;
    int*   blockoff = (int*)(ws + off); off += 64;
    int*   ssrc     = (int*)(ws + off); off += (size_t)E;
    float* h1       = ws + off; off += (size_t)N * 64;
    float* a_src1   = ws + off; off += (size_t)N * 8;
    float* a_dst1   = ws + off; off += (size_t)N * 8;
    float* xx       = ws + off; off += (size_t)N * 64;
    float* h2       = ws + off; off += (size_t)N * 40;
    float* a_src2   = ws + off; off += (size_t)N;
    float* a_dst2   = ws + off; off += (size_t)N;

    const int B = 256;
    auto g = [](int n) { return (n + 255) / 256; };
    int nb = (N + 1023) / 1024;   // 49

    // CSR build (dst-grouped)
    k_zero<<<g(N), B, 0, stream>>>(deg, N);
    k_deg<<<g(E), B, 0, stream>>>(dst, deg, E);
    k_scan_local<<<nb, 1024, 0, stream>>>(deg, rowptr, blocksum, N);
    k_scan_sums<<<1, 64, 0, stream>>>(blocksum, blockoff, nb);
    k_scan_add<<<g(N), B, 0, stream>>>(rowptr, blockoff, deg, cursor, N);
    k_scatter<<<g(E), B, 0, stream>>>(src, dst, cursor, ssrc, E);

    int gemmBlocks = (N + 63) / 64;

    // layer 1
    k_gemm1<<<gemmBlocks, B, 0, stream>>>(x, W1, att_src1, att_dst1, h1, a_src1, a_dst1, N);
    k_node_agg1<<<(N + 3) / 4, B, 0, stream>>>(rowptr, ssrc, a_src1, a_dst1, h1, bias1, xx, N);

    // layer 2 (gemm + attn dots fused)
    k_gemm2<<<gemmBlocks, B, 0, stream>>>(xx, W2, att_src2, att_dst2, h2, a_src2, a_dst2, N);
    k_node_agg2<<<(N + 3) / 4, B, 0, stream>>>(rowptr, ssrc, a_src2, a_dst2, h2, bias2, out, N);
}

// Round 8
// 272.540 us; speedup vs baseline: 1.3609x; 1.1070x over previous
//
#include <hip/hip_runtime.h>
#include <math.h>

#define EPS 1e-16f
__device__ __forceinline__ float lrelu(float v) { return v > 0.0f ? v : 0.2f * v; }

// bf16 pack/unpack (RNE; inputs finite)
__device__ __forceinline__ unsigned short f2bf(float f) {
    unsigned u = __float_as_uint(f);
    u += 0x7FFF + ((u >> 16) & 1);
    return (unsigned short)(u >> 16);
}
__device__ __forceinline__ float bf2f(unsigned short s) {
    return __uint_as_float(((unsigned)s) << 16);
}

// ---------------- CSR build ----------------
__global__ void k_zero(int* __restrict__ deg, int N) {
    int i = blockIdx.x * 256 + threadIdx.x;
    if (i < N) deg[i] = 0;
}

// multi-block scan: per-block local inclusive scan + block sums
__global__ __launch_bounds__(1024) void k_scan_local(const int* __restrict__ deg,
                                                     int* __restrict__ rowptr,
                                                     int* __restrict__ blocksum, int N) {
    __shared__ int sdata[1024];
    int i = blockIdx.x * 1024 + threadIdx.x;
    int v = (i < N) ? deg[i] : 0;
    sdata[threadIdx.x] = v;
    __syncthreads();
    for (int off = 1; off < 1024; off <<= 1) {
        int t = (threadIdx.x >= (unsigned)off) ? sdata[threadIdx.x - off] : 0;
        __syncthreads();
        sdata[threadIdx.x] += t;
        __syncthreads();
    }
    if (i < N) rowptr[i + 1] = sdata[threadIdx.x];
    if (threadIdx.x == 1023) blocksum[blockIdx.x] = sdata[1023];
}

// scan_add with inlined block-sum scan (every block redundantly wave-scans <=64 sums)
__global__ void k_scan_add(int* __restrict__ rowptr, const int* __restrict__ blocksum,
                           const int* __restrict__ deg, int* __restrict__ cursor,
                           int N, int nb) {
    __shared__ int sOff[64];
    int t = threadIdx.x;
    if (t < 64) {
        int v = (t < nb) ? blocksum[t] : 0;
        int incl = v;
#pragma unroll
        for (int off = 1; off < 64; off <<= 1) {
            int u = __shfl_up(incl, off);
            if (t >= off) incl += u;
        }
        sOff[t] = incl - v;
    }
    __syncthreads();
    int i = blockIdx.x * 256 + t;
    if (i >= N) return;
    int val = rowptr[i + 1] + sOff[i >> 10];
    rowptr[i + 1] = val;
    cursor[i] = val - deg[i];
    if (i == 0) rowptr[0] = 0;
}

// 4 edges per thread: int4 loads, 4 independent atomic-return chains in flight
__global__ void k_scatter(const int* __restrict__ src, const int* __restrict__ dst,
                          int* __restrict__ cursor, int* __restrict__ ssrc, int E) {
    int e0 = (blockIdx.x * 256 + threadIdx.x) * 4;
    if (e0 >= E) return;
    int4 s4 = *((const int4*)(src + e0));
    int4 d4 = *((const int4*)(dst + e0));
    int p0 = atomicAdd(&cursor[d4.x], 1);
    int p1 = atomicAdd(&cursor[d4.y], 1);
    int p2 = atomicAdd(&cursor[d4.z], 1);
    int p3 = atomicAdd(&cursor[d4.w], 1);
    ssrc[p0] = s4.x;
    ssrc[p1] = s4.y;
    ssrc[p2] = s4.z;
    ssrc[p3] = s4.w;
}

// ---------------- fused: layer-1 GEMM (blocks [0,G1)) + degree histogram (rest) ----------
// GEMM: x[N,128] @ W1[128,64] -> h1 (bf16), + fused attention dots. Register-tiled LDS GEMM:
// BM=64, BN=64, K=128 whole; 4x4 micro-tile; pitches 129/65 (==1 mod 32) -> <=2-way conflicts.
// deg: fire-and-forget atomics, co-scheduled with compute waves (latency hides).
#define LDK1 129
#define LDN1 65
__global__ __launch_bounds__(256, 2) void k_gemm1_deg(
    const float* __restrict__ x, const float* __restrict__ W1,
    const float* __restrict__ att_src1, const float* __restrict__ att_dst1,
    unsigned short* __restrict__ h1b, float* __restrict__ a_src1, float* __restrict__ a_dst1,
    int N, int G1, const int* __restrict__ dst, int* __restrict__ deg, int E) {
    __shared__ float sX[64 * LDK1];    // [m][k]
    __shared__ float sW[128 * LDN1];   // [k][n]
    int t = threadIdx.x;
    if (blockIdx.x >= G1) {
        int e0 = ((blockIdx.x - G1) * 256 + t) * 4;
        if (e0 < E) {
            int4 d4 = *((const int4*)(dst + e0));
            atomicAdd(&deg[d4.x], 1);
            atomicAdd(&deg[d4.y], 1);
            atomicAdd(&deg[d4.z], 1);
            atomicAdd(&deg[d4.w], 1);
        }
        return;
    }
    int r0 = blockIdx.x * 64;
    // stage W1 (128x64)
    for (int i = t; i < 2048; i += 256) {        // i = k*16 + n4
        int k = i >> 4, n4 = i & 15;
        float4 v = ((const float4*)W1)[i];
        float* p = sW + k * LDN1 + 4 * n4;
        p[0] = v.x; p[1] = v.y; p[2] = v.z; p[3] = v.w;
    }
    // stage x rows r0..r0+63 (zero-pad tail)
    for (int i = t; i < 2048; i += 256) {        // i = m*32 + k4
        int m = i >> 5, k4 = i & 31;
        int r = r0 + m;
        float4 v = make_float4(0.f, 0.f, 0.f, 0.f);
        if (r < N) v = ((const float4*)(x + (size_t)r * 128))[k4];
        float* p = sX + m * LDK1 + 4 * k4;
        p[0] = v.x; p[1] = v.y; p[2] = v.z; p[3] = v.w;
    }
    __syncthreads();
    int tx = t & 15, ty = t >> 4;                // rows 4*tx.., cols 4*ty..
    const float* pA = sX + 4 * tx * LDK1;
    const float* pB = sW + 4 * ty;
    float c[4][4] = {{0.f}};
#pragma unroll 8
    for (int k = 0; k < 128; k++) {
        float a0 = pA[k], a1 = pA[LDK1 + k], a2 = pA[2 * LDK1 + k], a3 = pA[3 * LDK1 + k];
        const float* pb = pB + k * LDN1;
        float b0 = pb[0], b1 = pb[1], b2 = pb[2], b3 = pb[3];
        c[0][0] = fmaf(a0, b0, c[0][0]); c[0][1] = fmaf(a0, b1, c[0][1]);
        c[0][2] = fmaf(a0, b2, c[0][2]); c[0][3] = fmaf(a0, b3, c[0][3]);
        c[1][0] = fmaf(a1, b0, c[1][0]); c[1][1] = fmaf(a1, b1, c[1][1]);
        c[1][2] = fmaf(a1, b2, c[1][2]); c[1][3] = fmaf(a1, b3, c[1][3]);
        c[2][0] = fmaf(a2, b0, c[2][0]); c[2][1] = fmaf(a2, b1, c[2][1]);
        c[2][2] = fmaf(a2, b2, c[2][2]); c[2][3] = fmaf(a2, b3, c[2][3]);
        c[3][0] = fmaf(a3, b0, c[3][0]); c[3][1] = fmaf(a3, b1, c[3][1]);
        c[3][2] = fmaf(a3, b2, c[3][2]); c[3][3] = fmaf(a3, b3, c[3][3]);
    }
    // epilogue: write h1 as bf16, fused per-head attention dots (fp32 accumulators).
    float as0 = att_src1[4 * ty + 0], as1 = att_src1[4 * ty + 1],
          as2 = att_src1[4 * ty + 2], as3 = att_src1[4 * ty + 3];
    float ad0 = att_dst1[4 * ty + 0], ad1 = att_dst1[4 * ty + 1],
          ad2 = att_dst1[4 * ty + 2], ad3 = att_dst1[4 * ty + 3];
    __syncthreads();                              // done reading sX/sW; reuse sX as partials
    float* sPs = sX;                              // [row][17]
    float* sPd = sX + 64 * 17;
#pragma unroll
    for (int i = 0; i < 4; i++) {
        int row = 4 * tx + i;
        int r = r0 + row;
        if (r < N) {
            ushort4 hv;
            hv.x = f2bf(c[i][0]); hv.y = f2bf(c[i][1]);
            hv.z = f2bf(c[i][2]); hv.w = f2bf(c[i][3]);
            *((ushort4*)(h1b + (size_t)r * 64 + 4 * ty)) = hv;
        }
        sPs[row * 17 + ty] = fmaf(c[i][0], as0, fmaf(c[i][1], as1, fmaf(c[i][2], as2, c[i][3] * as3)));
        sPd[row * 17 + ty] = fmaf(c[i][0], ad0, fmaf(c[i][1], ad1, fmaf(c[i][2], ad2, c[i][3] * ad3)));
    }
    __syncthreads();
    for (int i = t; i < 512; i += 256) {          // i = row*8 + h
        int row = i >> 3, h = i & 7;
        int r = r0 + row;
        if (r < N) {
            a_src1[r * 8 + h] = sPs[row * 17 + 2 * h] + sPs[row * 17 + 2 * h + 1];
            a_dst1[r * 8 + h] = sPd[row * 17 + 2 * h] + sPd[row * 17 + 2 * h + 1];
        }
    }
}

// ---------------- layer 1: per-dst-node softmax + aggregate (one wave per node) ----------------
// no max subtraction (softmax shift-invariant; logits are O(1)); h1 gathered as bf16 (halves
// the 205 MB cache-BW floor)
__global__ __launch_bounds__(256) void k_node_agg1(
    const int* __restrict__ rowptr, const int* __restrict__ ssrc,
    const float* __restrict__ a_src1, const float* __restrict__ a_dst1,
    const unsigned short* __restrict__ h1b, const float* __restrict__ bias1,
    float* __restrict__ xx, int N) {
    int d = (blockIdx.x * 256 + threadIdx.x) >> 6;
    int lane = threadIdx.x & 63;
    if (d >= N) return;
    int start = rowptr[d], end = rowptr[d + 1];
    int hcol = lane >> 3;   // head owning this output col
    int h8 = lane & 7;      // head this lane covers in edge-parallel phase
    int eoff = lane >> 3;   // edge-in-chunk this lane covers in edge-parallel phase
    float adst8 = a_dst1[d * 8 + h8];
    float acc0 = 0.0f, acc1 = 0.0f, lsumA = 0.0f;
    int base = start;
    for (; base + 8 <= end; base += 8) {
        // phase A: 8 edges x 8 heads in parallel
        int s_l = ssrc[base + eoff];
        float ex_l = __expf(lrelu(a_src1[(size_t)s_l * 8 + h8] + adst8));
        lsumA += ex_l;
        // phase B: broadcast (s,ex) via shuffle, 8 independent gathers
        int s0 = __shfl(s_l, 0),  s1 = __shfl(s_l, 8),  s2 = __shfl(s_l, 16), s3 = __shfl(s_l, 24);
        int s4 = __shfl(s_l, 32), s5 = __shfl(s_l, 40), s6 = __shfl(s_l, 48), s7 = __shfl(s_l, 56);
        float f0 = __shfl(ex_l, hcol),      f1 = __shfl(ex_l, 8 + hcol);
        float f2 = __shfl(ex_l, 16 + hcol), f3 = __shfl(ex_l, 24 + hcol);
        float f4 = __shfl(ex_l, 32 + hcol), f5 = __shfl(ex_l, 40 + hcol);
        float f6 = __shfl(ex_l, 48 + hcol), f7 = __shfl(ex_l, 56 + hcol);
        float g0 = bf2f(h1b[(size_t)s0 * 64 + lane]), g1 = bf2f(h1b[(size_t)s1 * 64 + lane]);
        float g2 = bf2f(h1b[(size_t)s2 * 64 + lane]), g3 = bf2f(h1b[(size_t)s3 * 64 + lane]);
        float g4 = bf2f(h1b[(size_t)s4 * 64 + lane]), g5 = bf2f(h1b[(size_t)s5 * 64 + lane]);
        float g6 = bf2f(h1b[(size_t)s6 * 64 + lane]), g7 = bf2f(h1b[(size_t)s7 * 64 + lane]);
        acc0 = fmaf(f0, g0, acc0); acc1 = fmaf(f1, g1, acc1);
        acc0 = fmaf(f2, g2, acc0); acc1 = fmaf(f3, g3, acc1);
        acc0 = fmaf(f4, g4, acc0); acc1 = fmaf(f5, g5, acc1);
        acc0 = fmaf(f6, g6, acc0); acc1 = fmaf(f7, g7, acc1);
    }
    int ecnt = end - base;
    if (ecnt > 0) {
        int s_l = 0; float ex_l = 0.0f;
        if (eoff < ecnt) {
            s_l = ssrc[base + eoff];
            ex_l = __expf(lrelu(a_src1[(size_t)s_l * 8 + h8] + adst8));
        }
        lsumA += ex_l;
        for (int j = 0; j < ecnt; j++) {
            int sj = __shfl(s_l, j * 8);
            float fj = __shfl(ex_l, j * 8 + hcol);
            acc0 = fmaf(fj, bf2f(h1b[(size_t)sj * 64 + lane]), acc0);
        }
    }
    // denom: reduce lsumA over edge-offset bits (3..5); then broadcast head hcol's sum
    float t = lsumA;
    t += __shfl_xor(t, 8); t += __shfl_xor(t, 16); t += __shfl_xor(t, 32);
    float lsum = __shfl(t, hcol);
    float o = (acc0 + acc1) / (lsum + EPS) + bias1[lane];
    xx[(size_t)d * 64 + lane] = o > 0.0f ? o : expm1f(o);   // ELU
}

// ---------------- layer 2 GEMM: xx[N,64] @ W2[64,40] -> h2, + fused attention dots ----
#define LDK2 65
#define LDN2 41
__global__ __launch_bounds__(256, 2) void k_gemm2(
    const float* __restrict__ xx, const float* __restrict__ W2,
    const float* __restrict__ att_src2, const float* __restrict__ att_dst2,
    float* __restrict__ h2, float* __restrict__ a_src2, float* __restrict__ a_dst2, int N) {
    __shared__ float sX[64 * LDK2];    // [m][k]
    __shared__ float sW[64 * LDN2];    // [k][n]
    int t = threadIdx.x;
    int r0 = blockIdx.x * 64;
    for (int i = t; i < 640; i += 256) {          // i = k*10 + n4
        int k = i / 10, n4 = i - k * 10;
        float4 v = ((const float4*)W2)[i];
        float* p = sW + k * LDN2 + 4 * n4;
        p[0] = v.x; p[1] = v.y; p[2] = v.z; p[3] = v.w;
    }
    for (int i = t; i < 1024; i += 256) {         // i = m*16 + k4
        int m = i >> 4, k4 = i & 15;
        int r = r0 + m;
        float4 v = make_float4(0.f, 0.f, 0.f, 0.f);
        if (r < N) v = ((const float4*)(xx + (size_t)r * 64))[k4];
        float* p = sX + m * LDK2 + 4 * k4;
        p[0] = v.x; p[1] = v.y; p[2] = v.z; p[3] = v.w;
    }
    __syncthreads();
    int tx = t & 15, ty = t >> 4;
    bool act = ty < 10;
    float c[4][4] = {{0.f}};
    if (act) {
        const float* pA = sX + 4 * tx * LDK2;
        const float* pB = sW + 4 * ty;
#pragma unroll 8
        for (int k = 0; k < 64; k++) {
            float a0 = pA[k], a1 = pA[LDK2 + k], a2 = pA[2 * LDK2 + k], a3 = pA[3 * LDK2 + k];
            const float* pb = pB + k * LDN2;
            float b0 = pb[0], b1 = pb[1], b2 = pb[2], b3 = pb[3];
            c[0][0] = fmaf(a0, b0, c[0][0]); c[0][1] = fmaf(a0, b1, c[0][1]);
            c[0][2] = fmaf(a0, b2, c[0][2]); c[0][3] = fmaf(a0, b3, c[0][3]);
            c[1][0] = fmaf(a1, b0, c[1][0]); c[1][1] = fmaf(a1, b1, c[1][1]);
            c[1][2] = fmaf(a1, b2, c[1][2]); c[1][3] = fmaf(a1, b3, c[1][3]);
            c[2][0] = fmaf(a2, b0, c[2][0]); c[2][1] = fmaf(a2, b1, c[2][1]);
            c[2][2] = fmaf(a2, b2, c[2][2]); c[2][3] = fmaf(a2, b3, c[2][3]);
            c[3][0] = fmaf(a3, b0, c[3][0]); c[3][1] = fmaf(a3, b1, c[3][1]);
            c[3][2] = fmaf(a3, b2, c[3][2]); c[3][3] = fmaf(a3, b3, c[3][3]);
        }
    }
    float as0 = 0.f, as1 = 0.f, as2 = 0.f, as3 = 0.f;
    float ad0 = 0.f, ad1 = 0.f, ad2 = 0.f, ad3 = 0.f;
    if (act) {
        as0 = att_src2[4 * ty + 0]; as1 = att_src2[4 * ty + 1];
        as2 = att_src2[4 * ty + 2]; as3 = att_src2[4 * ty + 3];
        ad0 = att_dst2[4 * ty + 0]; ad1 = att_dst2[4 * ty + 1];
        ad2 = att_dst2[4 * ty + 2]; ad3 = att_dst2[4 * ty + 3];
    }
    __syncthreads();                              // reuse sX as partials [row][11]
    float* sPs = sX;
    float* sPd = sX + 64 * 11;
#pragma unroll
    for (int i = 0; i < 4; i++) {
        int row = 4 * tx + i;
        int r = r0 + row;
        if (act) {
            if (r < N) {
                float4 hv = make_float4(c[i][0], c[i][1], c[i][2], c[i][3]);
                *((float4*)(h2 + (size_t)r * 40 + 4 * ty)) = hv;
            }
            sPs[row * 11 + ty] = fmaf(c[i][0], as0, fmaf(c[i][1], as1, fmaf(c[i][2], as2, c[i][3] * as3)));
            sPd[row * 11 + ty] = fmaf(c[i][0], ad0, fmaf(c[i][1], ad1, fmaf(c[i][2], ad2, c[i][3] * ad3)));
        }
    }
    __syncthreads();
    if (t < 64) {
        int r = r0 + t;
        if (r < N) {
            float ps = 0.f, pd = 0.f;
#pragma unroll
            for (int j = 0; j < 10; j++) {
                ps += sPs[t * 11 + j];
                pd += sPd[t * 11 + j];
            }
            a_src2[r] = ps;
            a_dst2[r] = pd;
        }
    }
}

// ---------------- layer 2: per-dst-node softmax + aggregate ----------------
__global__ __launch_bounds__(256) void k_node_agg2(
    const int* __restrict__ rowptr, const int* __restrict__ ssrc,
    const float* __restrict__ a_src2, const float* __restrict__ a_dst2,
    const float* __restrict__ h2, const float* __restrict__ bias2,
    float* __restrict__ out, int N) {
    int d = (blockIdx.x * 256 + threadIdx.x) >> 6;
    int lane = threadIdx.x & 63;
    if (d >= N) return;
    int start = rowptr[d], end = rowptr[d + 1];
    float adst = a_dst2[d];
    bool act = lane < 40;
    float acc0 = 0.0f, acc1 = 0.0f, lsumA = 0.0f;
    for (int base = start; base < end; base += 64) {
        int ecnt = min(64, end - base);
        int s_l = 0; float ex_l = 0.0f;
        if (lane < ecnt) {
            s_l = ssrc[base + lane];
            ex_l = __expf(lrelu(a_src2[s_l] + adst));
        }
        lsumA += ex_l;
        int j = 0;
        for (; j + 8 <= ecnt; j += 8) {
            int s0 = __shfl(s_l, j),     s1 = __shfl(s_l, j + 1), s2 = __shfl(s_l, j + 2), s3 = __shfl(s_l, j + 3);
            int s4 = __shfl(s_l, j + 4), s5 = __shfl(s_l, j + 5), s6 = __shfl(s_l, j + 6), s7 = __shfl(s_l, j + 7);
            float f0 = __shfl(ex_l, j),     f1 = __shfl(ex_l, j + 1), f2 = __shfl(ex_l, j + 2), f3 = __shfl(ex_l, j + 3);
            float f4 = __shfl(ex_l, j + 4), f5 = __shfl(ex_l, j + 5), f6 = __shfl(ex_l, j + 6), f7 = __shfl(ex_l, j + 7);
            float g0 = act ? h2[(size_t)s0 * 40 + lane] : 0.0f;
            float g1 = act ? h2[(size_t)s1 * 40 + lane] : 0.0f;
            float g2 = act ? h2[(size_t)s2 * 40 + lane] : 0.0f;
            float g3 = act ? h2[(size_t)s3 * 40 + lane] : 0.0f;
            float g4 = act ? h2[(size_t)s4 * 40 + lane] : 0.0f;
            float g5 = act ? h2[(size_t)s5 * 40 + lane] : 0.0f;
            float g6 = act ? h2[(size_t)s6 * 40 + lane] : 0.0f;
            float g7 = act ? h2[(size_t)s7 * 40 + lane] : 0.0f;
            acc0 = fmaf(f0, g0, acc0); acc1 = fmaf(f1, g1, acc1);
            acc0 = fmaf(f2, g2, acc0); acc1 = fmaf(f3, g3, acc1);
            acc0 = fmaf(f4, g4, acc0); acc1 = fmaf(f5, g5, acc1);
            acc0 = fmaf(f6, g6, acc0); acc1 = fmaf(f7, g7, acc1);
        }
        for (; j < ecnt; j++) {
            int sj = __shfl(s_l, j);
            float fj = __shfl(ex_l, j);
            float g = act ? h2[(size_t)sj * 40 + lane] : 0.0f;
            acc0 = fmaf(fj, g, acc0);
        }
    }
    float t = lsumA;
#pragma unroll
    for (int off = 32; off; off >>= 1) t += __shfl_xor(t, off);
    if (act) out[(size_t)d * 40 + lane] = (acc0 + acc1) / (t + EPS) + bias2[lane];
}

// ---------------- launch ----------------
extern "C" void kernel_launch(void* const* d_in, const int* in_sizes, int n_in,
                              void* d_out, int out_size, void* d_ws, size_t ws_size,
                              hipStream_t stream) {
    const float* x        = (const float*)d_in[0];
    const int*   ei       = (const int*)d_in[1];
    const float* W1       = (const float*)d_in[2];
    const float* att_src1 = (const float*)d_in[3];
    const float* att_dst1 = (const float*)d_in[4];
    const float* bias1    = (const float*)d_in[5];
    const float* W2       = (const float*)d_in[6];
    const float* att_src2 = (const float*)d_in[7];
    const float* att_dst2 = (const float*)d_in[8];
    const float* bias2    = (const float*)d_in[9];
    float* out = (float*)d_out;

    const int N = in_sizes[0] / 128;   // 50000
    const int E = in_sizes[1] / 2;     // 800000
    const int* src = ei;
    const int* dst = ei + E;

    // workspace layout
    float* ws = (float*)d_ws;
    size_t off = 0;
    int*   deg      = (int*)(ws + off); off += (size_t)N;
    int*   rowptr   = (int*)(ws + off); off += (size_t)N + 1;
    int*   cursor   = (int*)(ws + off); off += (size_t)N;
    int*   blocksum = (int*)(ws + off); off += 64;
    int*   ssrc     = (int*)(ws + off); off += (size_t)E;
    unsigned short* h1b = (unsigned short*)(ws + off); off += (size_t)N * 32;  // bf16 N*64
    float* a_src1   = ws + off; off += (size_t)N * 8;
    float* a_dst1   = ws + off; off += (size_t)N * 8;
    float* xx       = ws + off; off += (size_t)N * 64;
    float* h2       = ws + off; off += (size_t)N * 40;
    float* a_src2   = ws + off; off += (size_t)N;
    float* a_dst2   = ws + off; off += (size_t)N;

    const int B = 256;
    auto g = [](int n) { return (n + 255) / 256; };
    int nb = (N + 1023) / 1024;           // 49
    int G1 = (N + 63) / 64;               // gemm blocks
    int D  = (E / 4 + 255) / 256;         // deg/scatter blocks (4 edges/thread)

    k_zero<<<g(N), B, 0, stream>>>(deg, N);
    // gemm1 (+ attention dots) fused with degree histogram: independent work, co-scheduled
    k_gemm1_deg<<<G1 + D, B, 0, stream>>>(x, W1, att_src1, att_dst1, h1b, a_src1, a_dst1,
                                          N, G1, dst, deg, E);
    k_scan_local<<<nb, 1024, 0, stream>>>(deg, rowptr, blocksum, N);
    k_scan_add<<<g(N), B, 0, stream>>>(rowptr, blocksum, deg, cursor, N, nb);
    k_scatter<<<D, B, 0, stream>>>(src, dst, cursor, ssrc, E);

    k_node_agg1<<<(N + 3) / 4, B, 0, stream>>>(rowptr, ssrc, a_src1, a_dst1, h1b, bias1, xx, N);
    k_gemm2<<<G1, B, 0, stream>>>(xx, W2, att_src2, att_dst2, h2, a_src2, a_dst2, N);
    k_node_agg2<<<(N + 3) / 4, B, 0, stream>>>(rowptr, ssrc, a_src2, a_dst2, h2, bias2, out, N);
}